// Round 1
// baseline (1348.319 us; speedup 1.0000x reference)
//
#include <hip/hip_runtime.h>

#define NN 32
#define CC 16
#define HH 256
#define WW 256
#define HWSZ (HH * WW)

__global__ __launch_bounds__(256) void IndirectGridSample_kernel(
    const float* __restrict__ inp,
    const float* __restrict__ grid,
    const int*   __restrict__ idx,
    float*       __restrict__ out,
    int P)
{
    int p = blockIdx.x * blockDim.x + threadIdx.x;
    if (p >= P) return;

    // Coalesced float2 load of (gx, gy)
    float2 g = ((const float2*)grid)[p];
    float x = (g.x + 1.0f) * 0.5f * (float)(WW - 1);
    float y = (g.y + 1.0f) * 0.5f * (float)(HH - 1);

    float x0f = floorf(x);
    float y0f = floorf(y);
    float wx = x - x0f;
    float wy = y - y0f;

    int x0 = (int)x0f;
    int y0 = (int)y0f;
    int x1 = x0 + 1;
    int y1 = y0 + 1;

    // validity masks (grid is in [-1,1) so these are almost always true,
    // but keep exact reference semantics)
    float vx0 = (x0 >= 0 && x0 <= WW - 1) ? 1.0f : 0.0f;
    float vx1 = (x1 >= 0 && x1 <= WW - 1) ? 1.0f : 0.0f;
    float vy0 = (y0 >= 0 && y0 <= HH - 1) ? 1.0f : 0.0f;
    float vy1 = (y1 >= 0 && y1 <= HH - 1) ? 1.0f : 0.0f;

    int x0c = min(max(x0, 0), WW - 1);
    int x1c = min(max(x1, 0), WW - 1);
    int y0c = min(max(y0, 0), HH - 1);
    int y1c = min(max(y1, 0), HH - 1);

    float w00 = (1.0f - wx) * (1.0f - wy) * vx0 * vy0;
    float w01 = wx * (1.0f - wy) * vx1 * vy0;
    float w10 = (1.0f - wx) * wy * vx0 * vy1;
    float w11 = wx * wy * vx1 * vy1;

    const float* base = inp + (size_t)idx[p] * (size_t)(CC * HWSZ);
    int o00 = y0c * WW + x0c;
    int o01 = y0c * WW + x1c;
    int o10 = y1c * WW + x0c;
    int o11 = y1c * WW + x1c;

    float res[CC];
#pragma unroll
    for (int c = 0; c < CC; ++c) {
        const float* b = base + c * HWSZ;
        res[c] = b[o00] * w00 + b[o01] * w01 + b[o10] * w10 + b[o11] * w11;
    }

    // 64 B contiguous per thread -> coalesced float4 stores
    float4* outv = (float4*)(out + (size_t)p * CC);
#pragma unroll
    for (int i = 0; i < 4; ++i) {
        outv[i] = make_float4(res[4 * i + 0], res[4 * i + 1],
                              res[4 * i + 2], res[4 * i + 3]);
    }
}

extern "C" void kernel_launch(void* const* d_in, const int* in_sizes, int n_in,
                              void* d_out, int out_size, void* d_ws, size_t ws_size,
                              hipStream_t stream) {
    const float* inp  = (const float*)d_in[0];
    const float* grid = (const float*)d_in[1];
    const int*   idx  = (const int*)d_in[2];
    float* out = (float*)d_out;

    int P = in_sizes[2];  // number of points
    int block = 256;
    int gridsz = (P + block - 1) / block;
    IndirectGridSample_kernel<<<gridsz, block, 0, stream>>>(inp, grid, idx, out, P);
}

// Round 2
// 381.536 us; speedup vs baseline: 3.5339x; 3.5339x over previous
//
#include <hip/hip_runtime.h>

#define NN 32
#define CC 16
#define HH 256
#define WW 256
#define HWSZ (HH * WW)

// ---------------- Transpose NCHW -> NHWC (into workspace) ----------------
__global__ __launch_bounds__(256) void nchw_to_nhwc_kernel(
    const float* __restrict__ inp,
    float*       __restrict__ dst)
{
    int t = blockIdx.x * blockDim.x + threadIdx.x;   // 0 .. N*H*W-1
    int x = t & (WW - 1);
    int y = (t >> 8) & (HH - 1);
    int n = t >> 16;

    const float* src = inp + (size_t)n * CC * HWSZ + y * WW + x;
    float v[CC];
#pragma unroll
    for (int c = 0; c < CC; ++c) v[c] = src[(size_t)c * HWSZ];   // coalesced per c

    float4* d = (float4*)(dst + (size_t)t * CC);
#pragma unroll
    for (int i = 0; i < 4; ++i)
        d[i] = make_float4(v[4 * i + 0], v[4 * i + 1], v[4 * i + 2], v[4 * i + 3]);
}

// ---------------- Sample from NHWC ----------------
__global__ __launch_bounds__(256) void sample_nhwc_kernel(
    const float* __restrict__ src,    // NHWC
    const float* __restrict__ grid,
    const int*   __restrict__ idx,
    float*       __restrict__ out,
    int P)
{
    int p = blockIdx.x * blockDim.x + threadIdx.x;
    if (p >= P) return;

    float2 g = ((const float2*)grid)[p];
    float x = (g.x + 1.0f) * 0.5f * (float)(WW - 1);
    float y = (g.y + 1.0f) * 0.5f * (float)(HH - 1);

    float x0f = floorf(x);
    float y0f = floorf(y);
    float wx = x - x0f;
    float wy = y - y0f;

    int x0 = (int)x0f;
    int y0 = (int)y0f;
    int x1 = x0 + 1;
    int y1 = y0 + 1;

    float vx0 = (x0 >= 0 && x0 <= WW - 1) ? 1.0f : 0.0f;
    float vx1 = (x1 >= 0 && x1 <= WW - 1) ? 1.0f : 0.0f;
    float vy0 = (y0 >= 0 && y0 <= HH - 1) ? 1.0f : 0.0f;
    float vy1 = (y1 >= 0 && y1 <= HH - 1) ? 1.0f : 0.0f;

    int x0c = min(max(x0, 0), WW - 1);
    int x1c = min(max(x1, 0), WW - 1);
    int y0c = min(max(y0, 0), HH - 1);
    int y1c = min(max(y1, 0), HH - 1);

    float w00 = (1.0f - wx) * (1.0f - wy) * vx0 * vy0;
    float w01 = wx * (1.0f - wy) * vx1 * vy0;
    float w10 = (1.0f - wx) * wy * vx0 * vy1;
    float w11 = wx * wy * vx1 * vy1;

    const float* base = src + (size_t)idx[p] * (size_t)(HWSZ * CC);
    const float4* c00 = (const float4*)(base + ((size_t)y0c * WW + x0c) * CC);
    const float4* c01 = (const float4*)(base + ((size_t)y0c * WW + x1c) * CC);
    const float4* c10 = (const float4*)(base + ((size_t)y1c * WW + x0c) * CC);
    const float4* c11 = (const float4*)(base + ((size_t)y1c * WW + x1c) * CC);

    float4* outv = (float4*)(out + (size_t)p * CC);
#pragma unroll
    for (int j = 0; j < 4; ++j) {
        float4 a = c00[j], b = c01[j], c = c10[j], d = c11[j];
        float4 r;
        r.x = a.x * w00 + b.x * w01 + c.x * w10 + d.x * w11;
        r.y = a.y * w00 + b.y * w01 + c.y * w10 + d.y * w11;
        r.z = a.z * w00 + b.z * w01 + c.z * w10 + d.z * w11;
        r.w = a.w * w00 + b.w * w01 + c.w * w10 + d.w * w11;
        outv[j] = r;
    }
}

// ---------------- Fallback (round-1 NCHW direct) ----------------
__global__ __launch_bounds__(256) void sample_nchw_kernel(
    const float* __restrict__ inp,
    const float* __restrict__ grid,
    const int*   __restrict__ idx,
    float*       __restrict__ out,
    int P)
{
    int p = blockIdx.x * blockDim.x + threadIdx.x;
    if (p >= P) return;

    float2 g = ((const float2*)grid)[p];
    float x = (g.x + 1.0f) * 0.5f * (float)(WW - 1);
    float y = (g.y + 1.0f) * 0.5f * (float)(HH - 1);

    float x0f = floorf(x), y0f = floorf(y);
    float wx = x - x0f, wy = y - y0f;
    int x0 = (int)x0f, y0 = (int)y0f, x1 = x0 + 1, y1 = y0 + 1;

    float vx0 = (x0 >= 0 && x0 <= WW - 1) ? 1.0f : 0.0f;
    float vx1 = (x1 >= 0 && x1 <= WW - 1) ? 1.0f : 0.0f;
    float vy0 = (y0 >= 0 && y0 <= HH - 1) ? 1.0f : 0.0f;
    float vy1 = (y1 >= 0 && y1 <= HH - 1) ? 1.0f : 0.0f;

    int x0c = min(max(x0, 0), WW - 1);
    int x1c = min(max(x1, 0), WW - 1);
    int y0c = min(max(y0, 0), HH - 1);
    int y1c = min(max(y1, 0), HH - 1);

    float w00 = (1.0f - wx) * (1.0f - wy) * vx0 * vy0;
    float w01 = wx * (1.0f - wy) * vx1 * vy0;
    float w10 = (1.0f - wx) * wy * vx0 * vy1;
    float w11 = wx * wy * vx1 * vy1;

    const float* base = inp + (size_t)idx[p] * (size_t)(CC * HWSZ);
    int o00 = y0c * WW + x0c, o01 = y0c * WW + x1c;
    int o10 = y1c * WW + x0c, o11 = y1c * WW + x1c;

    float res[CC];
#pragma unroll
    for (int c = 0; c < CC; ++c) {
        const float* b = base + c * HWSZ;
        res[c] = b[o00] * w00 + b[o01] * w01 + b[o10] * w10 + b[o11] * w11;
    }
    float4* outv = (float4*)(out + (size_t)p * CC);
#pragma unroll
    for (int i = 0; i < 4; ++i)
        outv[i] = make_float4(res[4 * i], res[4 * i + 1], res[4 * i + 2], res[4 * i + 3]);
}

extern "C" void kernel_launch(void* const* d_in, const int* in_sizes, int n_in,
                              void* d_out, int out_size, void* d_ws, size_t ws_size,
                              hipStream_t stream) {
    const float* inp  = (const float*)d_in[0];
    const float* grid = (const float*)d_in[1];
    const int*   idx  = (const int*)d_in[2];
    float* out = (float*)d_out;

    int P = in_sizes[2];
    const size_t needed = (size_t)NN * CC * HWSZ * sizeof(float);  // 128 MiB

    if (ws_size >= needed) {
        float* nhwc = (float*)d_ws;
        int tpix = NN * HH * WW;
        nchw_to_nhwc_kernel<<<tpix / 256, 256, 0, stream>>>(inp, nhwc);
        sample_nhwc_kernel<<<(P + 255) / 256, 256, 0, stream>>>(nhwc, grid, idx, out, P);
    } else {
        sample_nchw_kernel<<<(P + 255) / 256, 256, 0, stream>>>(inp, grid, idx, out, P);
    }
}

// Round 3
// 357.333 us; speedup vs baseline: 3.7733x; 1.0677x over previous
//
#include <hip/hip_runtime.h>
#include <hip/hip_bf16.h>

#define NN 32
#define CC 16
#define HH 256
#define WW 256
#define HWSZ (HH * WW)

// ---------- Transpose + downconvert: NCHW fp32 -> NHWC bf16 (into ws) ----------
// 4 consecutive x-pixels per thread: float4 reads per channel (coalesced,
// 1 KB/wave/instr), 128 B contiguous bf16 write per thread.
__global__ __launch_bounds__(256) void nchw_to_nhwc_bf16_kernel(
    const float* __restrict__ inp,
    __hip_bfloat16* __restrict__ dst)
{
    int t = blockIdx.x * blockDim.x + threadIdx.x;   // 0 .. N*H*W/4 - 1
    int pix = t * 4;
    int x = pix & (WW - 1);
    int y = (pix >> 8) & (HH - 1);
    int n = pix >> 16;

    const float* src = inp + (size_t)n * CC * HWSZ + y * WW + x;
    float4 v[CC];
#pragma unroll
    for (int c = 0; c < CC; ++c)
        v[c] = *(const float4*)(src + (size_t)c * HWSZ);

#pragma unroll
    for (int j = 0; j < 4; ++j) {
        union {
            __hip_bfloat16 h[CC];
            uint4 q[2];
        } u;
        const float* vf = (const float*)v;  // v[c] component j = vf[4*c + j]
#pragma unroll
        for (int c = 0; c < CC; ++c)
            u.h[c] = __float2bfloat16(vf[4 * c + j]);
        uint4* d = (uint4*)(dst + (size_t)(pix + j) * CC);
        d[0] = u.q[0];
        d[1] = u.q[1];
    }
}

// ---------- Sample from NHWC bf16 ----------
__global__ __launch_bounds__(256) void sample_nhwc_bf16_kernel(
    const __hip_bfloat16* __restrict__ src,    // NHWC bf16
    const float* __restrict__ grid,
    const int*   __restrict__ idx,
    float*       __restrict__ out,
    int P)
{
    int p = blockIdx.x * blockDim.x + threadIdx.x;
    if (p >= P) return;

    float2 g = ((const float2*)grid)[p];
    float x = (g.x + 1.0f) * 0.5f * (float)(WW - 1);
    float y = (g.y + 1.0f) * 0.5f * (float)(HH - 1);

    float x0f = floorf(x);
    float y0f = floorf(y);
    float wx = x - x0f;
    float wy = y - y0f;

    int x0 = (int)x0f, y0 = (int)y0f;
    int x1 = x0 + 1, y1 = y0 + 1;

    float vx0 = (x0 >= 0 && x0 <= WW - 1) ? 1.0f : 0.0f;
    float vx1 = (x1 >= 0 && x1 <= WW - 1) ? 1.0f : 0.0f;
    float vy0 = (y0 >= 0 && y0 <= HH - 1) ? 1.0f : 0.0f;
    float vy1 = (y1 >= 0 && y1 <= HH - 1) ? 1.0f : 0.0f;

    int x0c = min(max(x0, 0), WW - 1);
    int x1c = min(max(x1, 0), WW - 1);
    int y0c = min(max(y0, 0), HH - 1);
    int y1c = min(max(y1, 0), HH - 1);

    float w00 = (1.0f - wx) * (1.0f - wy) * vx0 * vy0;
    float w01 = wx * (1.0f - wy) * vx1 * vy0;
    float w10 = (1.0f - wx) * wy * vx0 * vy1;
    float w11 = wx * wy * vx1 * vy1;

    const __hip_bfloat16* base = src + (size_t)idx[p] * (size_t)(HWSZ * CC);

    float res[CC];
#pragma unroll
    for (int c = 0; c < CC; ++c) res[c] = 0.0f;

    // one corner: 32 B = 2x uint4 loads, unpack bf16x2, FMA into res
    auto acc_corner = [&](int off, float w) {
        union {
            uint4 q[2];
            __hip_bfloat162 h2[8];
        } u;
        const uint4* ptr = (const uint4*)(base + (size_t)off * CC);
        u.q[0] = ptr[0];
        u.q[1] = ptr[1];
#pragma unroll
        for (int i = 0; i < 8; ++i) {
            float2 f = __bfloat1622float2(u.h2[i]);
            res[2 * i + 0] += f.x * w;
            res[2 * i + 1] += f.y * w;
        }
    };

    acc_corner(y0c * WW + x0c, w00);
    acc_corner(y0c * WW + x1c, w01);
    acc_corner(y1c * WW + x0c, w10);
    acc_corner(y1c * WW + x1c, w11);

    float4* outv = (float4*)(out + (size_t)p * CC);
#pragma unroll
    for (int i = 0; i < 4; ++i)
        outv[i] = make_float4(res[4 * i + 0], res[4 * i + 1],
                              res[4 * i + 2], res[4 * i + 3]);
}

// ---------- Fallback (NCHW direct, no workspace needed) ----------
__global__ __launch_bounds__(256) void sample_nchw_kernel(
    const float* __restrict__ inp,
    const float* __restrict__ grid,
    const int*   __restrict__ idx,
    float*       __restrict__ out,
    int P)
{
    int p = blockIdx.x * blockDim.x + threadIdx.x;
    if (p >= P) return;

    float2 g = ((const float2*)grid)[p];
    float x = (g.x + 1.0f) * 0.5f * (float)(WW - 1);
    float y = (g.y + 1.0f) * 0.5f * (float)(HH - 1);

    float x0f = floorf(x), y0f = floorf(y);
    float wx = x - x0f, wy = y - y0f;
    int x0 = (int)x0f, y0 = (int)y0f, x1 = x0 + 1, y1 = y0 + 1;

    float vx0 = (x0 >= 0 && x0 <= WW - 1) ? 1.0f : 0.0f;
    float vx1 = (x1 >= 0 && x1 <= WW - 1) ? 1.0f : 0.0f;
    float vy0 = (y0 >= 0 && y0 <= HH - 1) ? 1.0f : 0.0f;
    float vy1 = (y1 >= 0 && y1 <= HH - 1) ? 1.0f : 0.0f;

    int x0c = min(max(x0, 0), WW - 1);
    int x1c = min(max(x1, 0), WW - 1);
    int y0c = min(max(y0, 0), HH - 1);
    int y1c = min(max(y1, 0), HH - 1);

    float w00 = (1.0f - wx) * (1.0f - wy) * vx0 * vy0;
    float w01 = wx * (1.0f - wy) * vx1 * vy0;
    float w10 = (1.0f - wx) * wy * vx0 * vy1;
    float w11 = wx * wy * vx1 * vy1;

    const float* base = inp + (size_t)idx[p] * (size_t)(CC * HWSZ);
    int o00 = y0c * WW + x0c, o01 = y0c * WW + x1c;
    int o10 = y1c * WW + x0c, o11 = y1c * WW + x1c;

    float res[CC];
#pragma unroll
    for (int c = 0; c < CC; ++c) {
        const float* b = base + c * HWSZ;
        res[c] = b[o00] * w00 + b[o01] * w01 + b[o10] * w10 + b[o11] * w11;
    }
    float4* outv = (float4*)(out + (size_t)p * CC);
#pragma unroll
    for (int i = 0; i < 4; ++i)
        outv[i] = make_float4(res[4 * i], res[4 * i + 1], res[4 * i + 2], res[4 * i + 3]);
}

extern "C" void kernel_launch(void* const* d_in, const int* in_sizes, int n_in,
                              void* d_out, int out_size, void* d_ws, size_t ws_size,
                              hipStream_t stream) {
    const float* inp  = (const float*)d_in[0];
    const float* grid = (const float*)d_in[1];
    const int*   idx  = (const int*)d_in[2];
    float* out = (float*)d_out;

    int P = in_sizes[2];
    const size_t needed = (size_t)NN * CC * HWSZ * sizeof(__hip_bfloat16);  // 64 MiB

    if (ws_size >= needed) {
        __hip_bfloat16* nhwc = (__hip_bfloat16*)d_ws;
        int tquads = NN * HH * WW / 4;
        nchw_to_nhwc_bf16_kernel<<<tquads / 256, 256, 0, stream>>>(inp, nhwc);
        sample_nhwc_bf16_kernel<<<(P + 255) / 256, 256, 0, stream>>>(nhwc, grid, idx, out, P);
    } else {
        sample_nchw_kernel<<<(P + 255) / 256, 256, 0, stream>>>(inp, grid, idx, out, P);
    }
}